// Round 22
// baseline (52.803 us; speedup 1.0000x reference)
//
#include <hip/hip_runtime.h>
#include <hip/hip_bf16.h>

#define BATCH 4
#define SEQ   4096
#define DIN   768
#define DOUT  64

typedef __attribute__((ext_vector_type(4))) float f32x4;
typedef __attribute__((ext_vector_type(8))) short short8;
typedef __attribute__((ext_vector_type(4))) short short4v;
typedef __attribute__((ext_vector_type(2))) unsigned uint2v;

#define QSCALE 0.18033688011112043f  /* 0.125 * log2(e) */

static __device__ __forceinline__ unsigned short f2bf(float f) {
    union { float f; unsigned u; } un; un.f = f;
    unsigned r = un.u + 0x7FFF + ((un.u >> 16) & 1);
    return (unsigned short)(r >> 16);
}
static __device__ __forceinline__ float bf2f(unsigned short h) {
    union { unsigned u; float f; } un; un.u = ((unsigned)h) << 16;
    return un.f;
}
static __device__ __forceinline__ unsigned packbf(float lo, float hi) {
    return ((unsigned)f2bf(hi) << 16) | (unsigned)f2bf(lo);
}

// ---------------------------------------------------------------------------
// Kernel 0 (v2, unchanged): weights -> B-fragment order.
// ---------------------------------------------------------------------------
__global__ void wprep_kernel(const float* __restrict__ wq,
                             const float* __restrict__ wk,
                             const float* __restrict__ wv,
                             unsigned short* __restrict__ wF) {
    __shared__ float lds[64][65];
    int o = blockIdx.x / 12, kt = blockIdx.x % 12;
    const float* w = (o == 0) ? wq : (o == 1) ? wk : wv;
    int tid = threadIdx.x;
    int k0 = kt * 64;
    #pragma unroll
    for (int i = 0; i < 16; ++i) {
        int flat = tid + i * 256;
        int kl = flat >> 6, n = flat & 63;
        lds[kl][n] = w[(k0 + kl) * 64 + n];
    }
    __syncthreads();
    int lane = tid & 63;
    int m = lane & 15, g = lane >> 4;
    #pragma unroll
    for (int i = 0; i < 2; ++i) {
        int f = i * 4 + (tid >> 6);
        int t = f >> 1, kcl = f & 1;
        int kc = kt * 2 + kcl;
        int nc = o * 4 + t;
        short8 v;
        #pragma unroll
        for (int j = 0; j < 8; ++j)
            v[j] = (short)f2bf(lds[kcl * 32 + g * 8 + j][t * 16 + m]);
        *(short8*)&wF[(size_t)(nc * 24 + kc) * 512 + lane * 8] = v;
    }
}

// ---------------------------------------------------------------------------
// Kernel 1 (v10, unchanged): QKV projection, 16 rows/block, 1024 blocks,
// in-place rotated wF/af prefetch.
// ---------------------------------------------------------------------------
__global__ void __launch_bounds__(256) proj_kernel(
        const float* __restrict__ x,
        const float* __restrict__ bq,
        const float* __restrict__ bk,
        const float* __restrict__ bv,
        const unsigned short* __restrict__ wF,
        unsigned short* __restrict__ Qf,
        unsigned short* __restrict__ Kf,
        unsigned short* __restrict__ Vf) {
    __shared__ __align__(16) unsigned short xs[16][776];
    __shared__ unsigned short tr[4][16][24];

    int tid = threadIdx.x;
    int w = tid >> 6;
    int lane = tid & 63;
    int m = lane & 15, g = lane >> 4;
    int r0 = blockIdx.x * 16;

    {
        const float* xbase = x + (size_t)r0 * DIN;
        #pragma unroll
        for (int i = 0; i < 12; ++i) {
            int flat4 = tid + i * 256;
            int row = flat4 / 192;
            int c4 = flat4 - row * 192;
            float4 v = *(const float4*)(xbase + (size_t)row * DIN + c4 * 4);
            short4v sv;
            sv[0] = (short)f2bf(v.x); sv[1] = (short)f2bf(v.y);
            sv[2] = (short)f2bf(v.z); sv[3] = (short)f2bf(v.w);
            *(short4v*)&xs[row][c4 * 4] = sv;
        }
    }
    __syncthreads();

    f32x4 acc[3];
    #pragma unroll
    for (int t = 0; t < 3; ++t) acc[t] = (f32x4){0.f, 0.f, 0.f, 0.f};

    const unsigned short* wb0 = wF + (size_t)((w * 3 + 0) * 24) * 512 + lane * 8;
    const unsigned short* wb1 = wF + (size_t)((w * 3 + 1) * 24) * 512 + lane * 8;
    const unsigned short* wb2 = wF + (size_t)((w * 3 + 2) * 24) * 512 + lane * 8;

    short8 bf0 = *(const short8*)(wb0);
    short8 bf1 = *(const short8*)(wb1);
    short8 bf2 = *(const short8*)(wb2);
    short8 af0 = *(const short8*)&xs[m][g * 8];

    for (int kc = 0; kc < 24; ++kc) {
        short8 nb0, nb1, nb2, na0;
        bool have = (kc + 1) < 24;
        if (have) {
            int off = (kc + 1) * 512;
            nb0 = *(const short8*)(wb0 + off);
            nb1 = *(const short8*)(wb1 + off);
            nb2 = *(const short8*)(wb2 + off);
            na0 = *(const short8*)&xs[m][(kc + 1) * 32 + g * 8];
        }
        acc[0] = __builtin_amdgcn_mfma_f32_16x16x32_bf16(af0, bf0, acc[0], 0, 0, 0);
        acc[1] = __builtin_amdgcn_mfma_f32_16x16x32_bf16(af0, bf1, acc[1], 0, 0, 0);
        acc[2] = __builtin_amdgcn_mfma_f32_16x16x32_bf16(af0, bf2, acc[2], 0, 0, 0);
        if (have) {
            bf0 = nb0; bf1 = nb1; bf2 = nb2; af0 = na0;
        }
    }

    int b2 = r0 >> 12;
    int ss = r0 & 4095;
    int s = ss >> 5, half = (ss >> 4) & 1;
    #pragma unroll
    for (int tt = 0; tt < 3; ++tt) {
        int nc = w * 3 + tt;
        int o = nc >> 2;
        int t = nc & 3;
        const float* bias_p = (o == 0) ? bq : (o == 1) ? bk : bv;
        float bias = bias_p[t * 16 + m];
        #pragma unroll
        for (int r = 0; r < 4; ++r) {
            float val = acc[tt][r] + bias;
            if (o == 0) val *= QSCALE;
            tr[w][g * 4 + r][m] = f2bf(val);
        }
        if (o < 2) {
            if (g < 2) {
                short8 v8;
                #pragma unroll
                for (int j = 0; j < 8; ++j) v8[j] = (short)tr[w][m][g * 8 + j];
                unsigned short* dst = (o == 0) ? Qf : Kf;
                int c = t >> 1;
                *(short8*)&dst[(size_t)(blockIdx.x * 2 + c) * 512
                               + (((t & 1) * 2 + g) * 16 + m) * 8] = v8;
            }
        } else {
            if (g < 2) {
                short8 v8;
                #pragma unroll
                for (int j = 0; j < 8; ++j) v8[j] = (short)tr[w][g * 8 + j][m];
                *(short8*)&Vf[((size_t)(b2 * 128 + s) * 4 + t) * 512
                              + ((half * 2 + g) * 16 + m) * 8] = v8;
            }
        }
    }
}

// ---------------------------------------------------------------------------
// Kernel 2 (v14): KVBLK=64 single-q-tile attention.
// Theory: residual attn cost is distributed PER-STEP FIXED OVERHEAD
// (defer-max branch, loop/mask/reload bookkeeping, LDS waits) -- each
// component individually null because each is ~10% of the chain. Doubling
// the KV step halves the number of steps per q-row at identical per-kv
// MFMA/exp2/LDS work -> overhead amortizes 2x.
// One 16-row q-tile per block (~125 VGPR fits 128/4-wave budget); balance
// via longest-first ordering + dynamic refill (1024 blocks, 2/CU).
// Carries over: swapped-QK, packed PT, ones-l, in-place K/V reloads.
// ---------------------------------------------------------------------------
__global__ void __launch_bounds__(512, 2) attn_kernel(
        const unsigned short* __restrict__ Qf,
        const unsigned short* __restrict__ Kf,
        const unsigned short* __restrict__ Vf,
        float* __restrict__ out) {
    __shared__ __align__(16) unsigned short PT[8][16][72];    // 18.4 KB
    __shared__ __align__(16) unsigned short pacc[8][16][68];  // 17.4 KB
    __shared__ float pm[8][16];
    __shared__ float pl[8][16];

    int j = blockIdx.x;
    int b = j & 3;
    int qt = 255 - (j >> 2);            // longest-first for LPT refill balance
    int q0 = qt * 16;
    int ns = (q0 + 79) >> 6;            // ceil((q0+16)/64) steps of 64 kv
    int tid = threadIdx.x;
    int w = tid >> 6;
    int lane = tid & 63;
    int m = lane & 15, g = lane >> 4;

    const unsigned short* Qp = Qf + (size_t)(b * 256 + qt) * 1024 + lane * 8;
    short8 qf0 = *(const short8*)(Qp);
    short8 qf1 = *(const short8*)(Qp + 512);

    short8 onesA;
    #pragma unroll
    for (int jj = 0; jj < 8; ++jj) onesA[jj] = (short)0x3F80;

    f32x4 acc[5];
    #pragma unroll
    for (int t = 0; t < 5; ++t) acc[t] = (f32x4){0.f, 0.f, 0.f, 0.f};
    float mrun = -INFINITY;

    const unsigned short* Kbase = Kf + (size_t)(b * 256) * 1024 + lane * 8;
    const unsigned short* Vbase = Vf + (size_t)(b * 128) * 2048 + lane * 8;

    // kf[2u+c]: kv-subtile u (16 rows), k-chunk c. vf[c*4+t]: kv-chunk c, d-subtile t.
    short8 kf[8], vf[8];
    if (w < ns) {
        #pragma unroll
        for (int u = 0; u < 4; ++u) {
            kf[2 * u]     = *(const short8*)(Kbase + (size_t)w * 4096 + u * 1024);
            kf[2 * u + 1] = *(const short8*)(Kbase + (size_t)w * 4096 + u * 1024 + 512);
        }
        #pragma unroll
        for (int c = 0; c < 2; ++c)
            #pragma unroll
            for (int t = 0; t < 4; ++t)
                vf[c * 4 + t] = *(const short8*)(Vbase + (size_t)(2 * w + c) * 2048 + t * 512);
    }

    for (int s = w; s < ns; s += 8) {
        int kv0 = s * 64;
        int sn = s + 8;
        bool have = (sn < ns);

        // QK^T: st[u][r] = S[kv0 + u*16 + g*4 + r][q0 + m]
        f32x4 st[4];
        #pragma unroll
        for (int u = 0; u < 4; ++u) {
            st[u] = (f32x4){0.f, 0.f, 0.f, 0.f};
            st[u] = __builtin_amdgcn_mfma_f32_16x16x32_bf16(kf[2 * u],     qf0, st[u], 0, 0, 0);
            st[u] = __builtin_amdgcn_mfma_f32_16x16x32_bf16(kf[2 * u + 1], qf1, st[u], 0, 0, 0);
        }

        // kf last read above -> in-place reload for s+8
        if (have) {
            #pragma unroll
            for (int u = 0; u < 4; ++u) {
                kf[2 * u]     = *(const short8*)(Kbase + (size_t)sn * 4096 + u * 1024);
                kf[2 * u + 1] = *(const short8*)(Kbase + (size_t)sn * 4096 + u * 1024 + 512);
            }
        }

        if (s == ns - 1) {
            int q = q0 + m;
            #pragma unroll
            for (int u = 0; u < 4; ++u)
                #pragma unroll
                for (int r = 0; r < 4; ++r)
                    if (kv0 + u * 16 + g * 4 + r > q) st[u][r] = -INFINITY;
        }

        // defer-max over all 16 scores
        float th = mrun + 8.0f;
        bool need = false;
        #pragma unroll
        for (int u = 0; u < 4; ++u)
            need = need | (st[u][0] > th) | (st[u][1] > th)
                        | (st[u][2] > th) | (st[u][3] > th);
        if (__any(need)) {
            float rmax = -INFINITY;
            #pragma unroll
            for (int u = 0; u < 4; ++u)
                rmax = fmaxf(rmax, fmaxf(fmaxf(st[u][0], st[u][1]), fmaxf(st[u][2], st[u][3])));
            rmax = fmaxf(rmax, __shfl_xor(rmax, 16));
            rmax = fmaxf(rmax, __shfl_xor(rmax, 32));
            float mnew = fmaxf(mrun, rmax);
            float alpha = __builtin_amdgcn_exp2f(mrun - mnew);
            mrun = mnew;
            #pragma unroll
            for (int t = 0; t < 5; ++t)
                #pragma unroll
                for (int r = 0; r < 4; ++r) acc[t][r] *= alpha;
        }

        // exp2 + pack + PT write per kv-subtile (4x ds_write_b64)
        #pragma unroll
        for (int u = 0; u < 4; ++u) {
            float e0 = __builtin_amdgcn_exp2f(st[u][0] - mrun);
            float e1 = __builtin_amdgcn_exp2f(st[u][1] - mrun);
            float e2 = __builtin_amdgcn_exp2f(st[u][2] - mrun);
            float e3 = __builtin_amdgcn_exp2f(st[u][3] - mrun);
            *(uint2v*)&PT[w][m][u * 16 + g * 4] = (uint2v){packbf(e0, e1), packbf(e2, e3)};
        }
        // PV B-frags: 2x ds_read_b128 (same-wave dep, lgkmcnt only)
        short8 pb0 = *(const short8*)&PT[w][m][g * 8];
        short8 pb1 = *(const short8*)&PT[w][m][32 + g * 8];

        #pragma unroll
        for (int t = 0; t < 4; ++t) {
            acc[t] = __builtin_amdgcn_mfma_f32_16x16x32_bf16(vf[t],     pb0, acc[t], 0, 0, 0);
            acc[t] = __builtin_amdgcn_mfma_f32_16x16x32_bf16(vf[4 + t], pb1, acc[t], 0, 0, 0);
        }
        acc[4] = __builtin_amdgcn_mfma_f32_16x16x32_bf16(onesA, pb0, acc[4], 0, 0, 0);
        acc[4] = __builtin_amdgcn_mfma_f32_16x16x32_bf16(onesA, pb1, acc[4], 0, 0, 0);

        // vf last read above -> in-place reload for s+8
        if (have) {
            #pragma unroll
            for (int c = 0; c < 2; ++c)
                #pragma unroll
                for (int t = 0; t < 4; ++t)
                    vf[c * 4 + t] = *(const short8*)(Vbase + (size_t)(2 * sn + c) * 2048 + t * 512);
        }
    }

    // ===== partials + combine (acc = O^T[d][q=m]; l = acc[4][0]) =====
    if (lane < 16) {
        pm[w][m] = mrun;
        pl[w][m] = acc[4][0];
    }
    #pragma unroll
    for (int t = 0; t < 4; ++t)
        #pragma unroll
        for (int r = 0; r < 4; ++r)
            pacc[w][m][t * 16 + g * 4 + r] = f2bf(acc[t][r]);
    __syncthreads();

    if (tid < 256) {
        int row = tid >> 4;
        int c4 = (tid & 15) * 4;
        float mmax = pm[0][row];
        #pragma unroll
        for (int w2 = 1; w2 < 8; ++w2) mmax = fmaxf(mmax, pm[w2][row]);
        float lt = 0.f;
        float o0 = 0.f, o1 = 0.f, o2 = 0.f, o3 = 0.f;
        #pragma unroll
        for (int w2 = 0; w2 < 8; ++w2) {
            float sc2 = __builtin_amdgcn_exp2f(pm[w2][row] - mmax);
            lt += pl[w2][row] * sc2;
            short4v pa4 = *(const short4v*)&pacc[w2][row][c4];
            o0 += bf2f((unsigned short)pa4[0]) * sc2;
            o1 += bf2f((unsigned short)pa4[1]) * sc2;
            o2 += bf2f((unsigned short)pa4[2]) * sc2;
            o3 += bf2f((unsigned short)pa4[3]) * sc2;
        }
        float invl = 1.0f / lt;
        float4 res = make_float4(o0 * invl, o1 * invl, o2 * invl, o3 * invl);
        *(float4*)&out[(size_t)(b * SEQ + q0 + row) * DOUT + c4] = res;
    }
}

// ---------------------------------------------------------------------------
extern "C" void kernel_launch(void* const* d_in, const int* in_sizes, int n_in,
                              void* d_out, int out_size, void* d_ws, size_t ws_size,
                              hipStream_t stream) {
    const float* x  = (const float*)d_in[0];
    const float* wq = (const float*)d_in[1];
    const float* bq = (const float*)d_in[2];
    const float* wk = (const float*)d_in[3];
    const float* bk = (const float*)d_in[4];
    const float* wv = (const float*)d_in[5];
    const float* bv = (const float*)d_in[6];
    float* out = (float*)d_out;

    char* ws = (char*)d_ws;
    unsigned short* wF = (unsigned short*)ws;                       // 294912 B
    unsigned short* Qf = (unsigned short*)(ws + 294912);            // 2 MB
    unsigned short* Kf = (unsigned short*)(ws + 294912 + 2097152);  // 2 MB
    unsigned short* Vf = (unsigned short*)(ws + 294912 + 4194304);  // 2 MB

    wprep_kernel<<<36, 256, 0, stream>>>(wq, wk, wv, wF);
    proj_kernel<<<1024, 256, 0, stream>>>(x, bq, bk, bv, wF, Qf, Kf, Vf);
    attn_kernel<<<1024, 512, 0, stream>>>(Qf, Kf, Vf, out);
}

// Round 23
// 48.715 us; speedup vs baseline: 1.0839x; 1.0839x over previous
//
#include <hip/hip_runtime.h>
#include <hip/hip_bf16.h>

#define BATCH 4
#define SEQ   4096
#define DIN   768
#define DOUT  64

typedef __attribute__((ext_vector_type(4))) float f32x4;
typedef __attribute__((ext_vector_type(8))) short short8;
typedef __attribute__((ext_vector_type(4))) short short4v;
typedef __attribute__((ext_vector_type(2))) unsigned uint2v;

#define QSCALE 0.18033688011112043f  /* 0.125 * log2(e) */

static __device__ __forceinline__ unsigned short f2bf(float f) {
    union { float f; unsigned u; } un; un.f = f;
    unsigned r = un.u + 0x7FFF + ((un.u >> 16) & 1);
    return (unsigned short)(r >> 16);
}
static __device__ __forceinline__ float bf2f(unsigned short h) {
    union { unsigned u; float f; } un; un.u = ((unsigned)h) << 16;
    return un.f;
}
static __device__ __forceinline__ unsigned packbf(float lo, float hi) {
    return ((unsigned)f2bf(hi) << 16) | (unsigned)f2bf(lo);
}

// ---------------------------------------------------------------------------
// Kernel 0 (v2): weights -> B-fragment order.
// ---------------------------------------------------------------------------
__global__ void wprep_kernel(const float* __restrict__ wq,
                             const float* __restrict__ wk,
                             const float* __restrict__ wv,
                             unsigned short* __restrict__ wF) {
    __shared__ float lds[64][65];
    int o = blockIdx.x / 12, kt = blockIdx.x % 12;
    const float* w = (o == 0) ? wq : (o == 1) ? wk : wv;
    int tid = threadIdx.x;
    int k0 = kt * 64;
    #pragma unroll
    for (int i = 0; i < 16; ++i) {
        int flat = tid + i * 256;
        int kl = flat >> 6, n = flat & 63;
        lds[kl][n] = w[(k0 + kl) * 64 + n];
    }
    __syncthreads();
    int lane = tid & 63;
    int m = lane & 15, g = lane >> 4;
    #pragma unroll
    for (int i = 0; i < 2; ++i) {
        int f = i * 4 + (tid >> 6);
        int t = f >> 1, kcl = f & 1;
        int kc = kt * 2 + kcl;
        int nc = o * 4 + t;
        short8 v;
        #pragma unroll
        for (int j = 0; j < 8; ++j)
            v[j] = (short)f2bf(lds[kcl * 32 + g * 8 + j][t * 16 + m]);
        *(short8*)&wF[(size_t)(nc * 24 + kc) * 512 + lane * 8] = v;
    }
}

// ---------------------------------------------------------------------------
// Kernel 1 (v9, round-19 best): QKV projection, 32 rows/block, 512 blocks,
// in-place rotated wF/af prefetch.
// ---------------------------------------------------------------------------
__global__ void __launch_bounds__(256) proj_kernel(
        const float* __restrict__ x,
        const float* __restrict__ bq,
        const float* __restrict__ bk,
        const float* __restrict__ bv,
        const unsigned short* __restrict__ wF,
        unsigned short* __restrict__ Qf,
        unsigned short* __restrict__ Kf,
        unsigned short* __restrict__ Vf) {
    __shared__ __align__(16) unsigned short xs[32][776];   // 48.5 KB
    __shared__ unsigned short tr[4][16][24];               // 3 KB

    int tid = threadIdx.x;
    int w = tid >> 6;
    int lane = tid & 63;
    int m = lane & 15, g = lane >> 4;
    int r0 = blockIdx.x * 32;

    {
        const float* xbase = x + (size_t)r0 * DIN;
        #pragma unroll
        for (int i = 0; i < 24; ++i) {
            int flat4 = tid + i * 256;
            int row = flat4 / 192;
            int c4 = flat4 - row * 192;
            float4 v = *(const float4*)(xbase + (size_t)row * DIN + c4 * 4);
            short4v sv;
            sv[0] = (short)f2bf(v.x); sv[1] = (short)f2bf(v.y);
            sv[2] = (short)f2bf(v.z); sv[3] = (short)f2bf(v.w);
            *(short4v*)&xs[row][c4 * 4] = sv;
        }
    }
    __syncthreads();

    f32x4 acc[2][3];
    #pragma unroll
    for (int st = 0; st < 2; ++st)
        #pragma unroll
        for (int t = 0; t < 3; ++t) acc[st][t] = (f32x4){0.f, 0.f, 0.f, 0.f};

    const unsigned short* wb0 = wF + (size_t)((w * 3 + 0) * 24) * 512 + lane * 8;
    const unsigned short* wb1 = wF + (size_t)((w * 3 + 1) * 24) * 512 + lane * 8;
    const unsigned short* wb2 = wF + (size_t)((w * 3 + 2) * 24) * 512 + lane * 8;

    short8 bf0 = *(const short8*)(wb0);
    short8 bf1 = *(const short8*)(wb1);
    short8 bf2 = *(const short8*)(wb2);
    short8 af0 = *(const short8*)&xs[m][g * 8];
    short8 af1 = *(const short8*)&xs[16 + m][g * 8];

    for (int kc = 0; kc < 24; ++kc) {
        short8 nb0, nb1, nb2, na0, na1;
        bool have = (kc + 1) < 24;
        if (have) {
            int off = (kc + 1) * 512;
            nb0 = *(const short8*)(wb0 + off);
            nb1 = *(const short8*)(wb1 + off);
            nb2 = *(const short8*)(wb2 + off);
            na0 = *(const short8*)&xs[m][(kc + 1) * 32 + g * 8];
            na1 = *(const short8*)&xs[16 + m][(kc + 1) * 32 + g * 8];
        }
        acc[0][0] = __builtin_amdgcn_mfma_f32_16x16x32_bf16(af0, bf0, acc[0][0], 0, 0, 0);
        acc[1][0] = __builtin_amdgcn_mfma_f32_16x16x32_bf16(af1, bf0, acc[1][0], 0, 0, 0);
        acc[0][1] = __builtin_amdgcn_mfma_f32_16x16x32_bf16(af0, bf1, acc[0][1], 0, 0, 0);
        acc[1][1] = __builtin_amdgcn_mfma_f32_16x16x32_bf16(af1, bf1, acc[1][1], 0, 0, 0);
        acc[0][2] = __builtin_amdgcn_mfma_f32_16x16x32_bf16(af0, bf2, acc[0][2], 0, 0, 0);
        acc[1][2] = __builtin_amdgcn_mfma_f32_16x16x32_bf16(af1, bf2, acc[1][2], 0, 0, 0);
        if (have) {
            bf0 = nb0; bf1 = nb1; bf2 = nb2;
            af0 = na0; af1 = na1;
        }
    }

    int b2 = r0 >> 12;
    int s = (r0 & 4095) >> 5;
    #pragma unroll
    for (int st = 0; st < 2; ++st) {
        #pragma unroll
        for (int tt = 0; tt < 3; ++tt) {
            int nc = w * 3 + tt;
            int o = nc >> 2;
            int t = nc & 3;
            const float* bias_p = (o == 0) ? bq : (o == 1) ? bk : bv;
            float bias = bias_p[t * 16 + m];
            #pragma unroll
            for (int r = 0; r < 4; ++r) {
                float val = acc[st][tt][r] + bias;
                if (o == 0) val *= QSCALE;
                tr[w][g * 4 + r][m] = f2bf(val);
            }
            if (o < 2) {
                if (g < 2) {
                    short8 v8;
                    #pragma unroll
                    for (int j = 0; j < 8; ++j) v8[j] = (short)tr[w][m][g * 8 + j];
                    unsigned short* dst = (o == 0) ? Qf : Kf;
                    int c = t >> 1;
                    *(short8*)&dst[(size_t)((blockIdx.x * 2 + st) * 2 + c) * 512
                                   + (((t & 1) * 2 + g) * 16 + m) * 8] = v8;
                }
            } else {
                if (g < 2) {
                    short8 v8;
                    #pragma unroll
                    for (int j = 0; j < 8; ++j) v8[j] = (short)tr[w][g * 8 + j][m];
                    *(short8*)&Vf[((size_t)(b2 * 128 + s) * 4 + t) * 512
                                  + ((st * 2 + g) * 16 + m) * 8] = v8;
                }
            }
        }
    }
}

// ---------------------------------------------------------------------------
// Kernel 2 (v12, round-19 best): swapped-QK + packed P_T LDS + ones-A
// row-sum, complementary pairing, in-place K/V rotation, (512,2).
// ---------------------------------------------------------------------------
__global__ void __launch_bounds__(512, 2) attn_kernel(
        const unsigned short* __restrict__ Qf,
        const unsigned short* __restrict__ Kf,
        const unsigned short* __restrict__ Vf,
        float* __restrict__ out) {
    __shared__ __align__(16) unsigned short PT[8][16][40];
    __shared__ __align__(16) unsigned short pacc[8][16][68];
    __shared__ float pm[8][16];
    __shared__ float pl[8][16];

    int j = blockIdx.x;
    int b = j & 3;
    int qt = j >> 2;
    int base0 = qt * 16;
    int base1 = (255 - qt) * 16;
    int ns0 = (qt + 2) >> 1;
    int ns1 = (257 - qt) >> 1;
    int tid = threadIdx.x;
    int w = tid >> 6;
    int lane = tid & 63;
    int m = lane & 15, g = lane >> 4;

    const unsigned short* Q0 = Qf + (size_t)(b * 256 + qt) * 1024 + lane * 8;
    const unsigned short* Q1 = Qf + (size_t)(b * 256 + 255 - qt) * 1024 + lane * 8;
    short8 qf00 = *(const short8*)(Q0);
    short8 qf01 = *(const short8*)(Q0 + 512);
    short8 qf10 = *(const short8*)(Q1);
    short8 qf11 = *(const short8*)(Q1 + 512);

    short8 onesA;
    #pragma unroll
    for (int jj = 0; jj < 8; ++jj) onesA[jj] = (short)0x3F80;

    f32x4 acc[2][5];
    #pragma unroll
    for (int rt = 0; rt < 2; ++rt)
        #pragma unroll
        for (int t = 0; t < 5; ++t) acc[rt][t] = (f32x4){0.f, 0.f, 0.f, 0.f};
    float mrun0 = -INFINITY, mrun1 = -INFINITY;

    const unsigned short* Kbase = Kf + (size_t)(b * 256) * 1024 + lane * 8;
    const unsigned short* Vbase = Vf + (size_t)(b * 128) * 2048 + lane * 8;

    short8 kf[4], vf[4];
    if (w < ns1) {
        #pragma unroll
        for (int t = 0; t < 4; ++t) {
            kf[t] = *(const short8*)(Kbase + (size_t)w * 2048 + t * 512);
            vf[t] = *(const short8*)(Vbase + (size_t)w * 2048 + t * 512);
        }
    }

    for (int s = w; s < ns1; s += 8) {
        int kv0 = s * 32;
        int sn = s + 8;
        bool have = (sn < ns1);
        bool do0 = (s < ns0);

        if (do0) {
            f32x4 st0 = (f32x4){0.f, 0.f, 0.f, 0.f};
            f32x4 st1 = (f32x4){0.f, 0.f, 0.f, 0.f};
            st0 = __builtin_amdgcn_mfma_f32_16x16x32_bf16(kf[0], qf00, st0, 0, 0, 0);
            st0 = __builtin_amdgcn_mfma_f32_16x16x32_bf16(kf[1], qf01, st0, 0, 0, 0);
            st1 = __builtin_amdgcn_mfma_f32_16x16x32_bf16(kf[2], qf00, st1, 0, 0, 0);
            st1 = __builtin_amdgcn_mfma_f32_16x16x32_bf16(kf[3], qf01, st1, 0, 0, 0);
            if (s == ns0 - 1) {
                int q = base0 + m;
                #pragma unroll
                for (int r = 0; r < 4; ++r) {
                    if (kv0 + g * 4 + r > q)      st0[r] = -INFINITY;
                    if (kv0 + 16 + g * 4 + r > q) st1[r] = -INFINITY;
                }
            }
            float th = mrun0 + 8.0f;
            bool need = (st0[0] > th) | (st0[1] > th) | (st0[2] > th) | (st0[3] > th)
                      | (st1[0] > th) | (st1[1] > th) | (st1[2] > th) | (st1[3] > th);
            if (__any(need)) {
                float rmax = fmaxf(fmaxf(fmaxf(st0[0], st0[1]), fmaxf(st0[2], st0[3])),
                                   fmaxf(fmaxf(st1[0], st1[1]), fmaxf(st1[2], st1[3])));
                rmax = fmaxf(rmax, __shfl_xor(rmax, 16));
                rmax = fmaxf(rmax, __shfl_xor(rmax, 32));
                float mnew = fmaxf(mrun0, rmax);
                float alpha = __builtin_amdgcn_exp2f(mrun0 - mnew);
                mrun0 = mnew;
                #pragma unroll
                for (int t = 0; t < 5; ++t)
                    #pragma unroll
                    for (int r = 0; r < 4; ++r) acc[0][t][r] *= alpha;
            }
            float p00 = __builtin_amdgcn_exp2f(st0[0] - mrun0);
            float p01 = __builtin_amdgcn_exp2f(st0[1] - mrun0);
            float p02 = __builtin_amdgcn_exp2f(st0[2] - mrun0);
            float p03 = __builtin_amdgcn_exp2f(st0[3] - mrun0);
            float p10 = __builtin_amdgcn_exp2f(st1[0] - mrun0);
            float p11 = __builtin_amdgcn_exp2f(st1[1] - mrun0);
            float p12 = __builtin_amdgcn_exp2f(st1[2] - mrun0);
            float p13 = __builtin_amdgcn_exp2f(st1[3] - mrun0);
            *(uint2v*)&PT[w][m][g * 4]      = (uint2v){packbf(p00, p01), packbf(p02, p03)};
            *(uint2v*)&PT[w][m][16 + g * 4] = (uint2v){packbf(p10, p11), packbf(p12, p13)};
            short8 pb = *(const short8*)&PT[w][m][g * 8];
            #pragma unroll
            for (int t = 0; t < 4; ++t)
                acc[0][t] = __builtin_amdgcn_mfma_f32_16x16x32_bf16(vf[t], pb, acc[0][t], 0, 0, 0);
            acc[0][4] = __builtin_amdgcn_mfma_f32_16x16x32_bf16(onesA, pb, acc[0][4], 0, 0, 0);
        }

        {
            f32x4 st0 = (f32x4){0.f, 0.f, 0.f, 0.f};
            f32x4 st1 = (f32x4){0.f, 0.f, 0.f, 0.f};
            st0 = __builtin_amdgcn_mfma_f32_16x16x32_bf16(kf[0], qf10, st0, 0, 0, 0);
            st0 = __builtin_amdgcn_mfma_f32_16x16x32_bf16(kf[1], qf11, st0, 0, 0, 0);
            st1 = __builtin_amdgcn_mfma_f32_16x16x32_bf16(kf[2], qf10, st1, 0, 0, 0);
            st1 = __builtin_amdgcn_mfma_f32_16x16x32_bf16(kf[3], qf11, st1, 0, 0, 0);

            if (have) {
                #pragma unroll
                for (int t = 0; t < 4; ++t)
                    kf[t] = *(const short8*)(Kbase + (size_t)sn * 2048 + t * 512);
            }

            if (s == ns1 - 1) {
                int q = base1 + m;
                #pragma unroll
                for (int r = 0; r < 4; ++r) {
                    if (kv0 + g * 4 + r > q)      st0[r] = -INFINITY;
                    if (kv0 + 16 + g * 4 + r > q) st1[r] = -INFINITY;
                }
            }
            float th = mrun1 + 8.0f;
            bool need = (st0[0] > th) | (st0[1] > th) | (st0[2] > th) | (st0[3] > th)
                      | (st1[0] > th) | (st1[1] > th) | (st1[2] > th) | (st1[3] > th);
            if (__any(need)) {
                float rmax = fmaxf(fmaxf(fmaxf(st0[0], st0[1]), fmaxf(st0[2], st0[3])),
                                   fmaxf(fmaxf(st1[0], st1[1]), fmaxf(st1[2], st1[3])));
                rmax = fmaxf(rmax, __shfl_xor(rmax, 16));
                rmax = fmaxf(rmax, __shfl_xor(rmax, 32));
                float mnew = fmaxf(mrun1, rmax);
                float alpha = __builtin_amdgcn_exp2f(mrun1 - mnew);
                mrun1 = mnew;
                #pragma unroll
                for (int t = 0; t < 5; ++t)
                    #pragma unroll
                    for (int r = 0; r < 4; ++r) acc[1][t][r] *= alpha;
            }
            float p00 = __builtin_amdgcn_exp2f(st0[0] - mrun1);
            float p01 = __builtin_amdgcn_exp2f(st0[1] - mrun1);
            float p02 = __builtin_amdgcn_exp2f(st0[2] - mrun1);
            float p03 = __builtin_amdgcn_exp2f(st0[3] - mrun1);
            float p10 = __builtin_amdgcn_exp2f(st1[0] - mrun1);
            float p11 = __builtin_amdgcn_exp2f(st1[1] - mrun1);
            float p12 = __builtin_amdgcn_exp2f(st1[2] - mrun1);
            float p13 = __builtin_amdgcn_exp2f(st1[3] - mrun1);
            *(uint2v*)&PT[w][m][g * 4]      = (uint2v){packbf(p00, p01), packbf(p02, p03)};
            *(uint2v*)&PT[w][m][16 + g * 4] = (uint2v){packbf(p10, p11), packbf(p12, p13)};
            short8 pb = *(const short8*)&PT[w][m][g * 8];
            #pragma unroll
            for (int t = 0; t < 4; ++t)
                acc[1][t] = __builtin_amdgcn_mfma_f32_16x16x32_bf16(vf[t], pb, acc[1][t], 0, 0, 0);
            acc[1][4] = __builtin_amdgcn_mfma_f32_16x16x32_bf16(onesA, pb, acc[1][4], 0, 0, 0);

            if (have) {
                #pragma unroll
                for (int t = 0; t < 4; ++t)
                    vf[t] = *(const short8*)(Vbase + (size_t)sn * 2048 + t * 512);
            }
        }
    }

    #pragma unroll
    for (int rt = 0; rt < 2; ++rt) {
        int qbase = (rt == 0) ? base0 : base1;
        float mr = (rt == 0) ? mrun0 : mrun1;
        if (lane < 16) {
            pm[w][m] = mr;
            pl[w][m] = acc[rt][4][0];
        }
        #pragma unroll
        for (int t = 0; t < 4; ++t)
            #pragma unroll
            for (int r = 0; r < 4; ++r)
                pacc[w][m][t * 16 + g * 4 + r] = f2bf(acc[rt][t][r]);
        __syncthreads();

        if (tid < 256) {
            int row = tid >> 4;
            int c4 = (tid & 15) * 4;
            float mmax = pm[0][row];
            #pragma unroll
            for (int w2 = 1; w2 < 8; ++w2) mmax = fmaxf(mmax, pm[w2][row]);
            float lt = 0.f;
            float o0 = 0.f, o1 = 0.f, o2 = 0.f, o3 = 0.f;
            #pragma unroll
            for (int w2 = 0; w2 < 8; ++w2) {
                float sc2 = __builtin_amdgcn_exp2f(pm[w2][row] - mmax);
                lt += pl[w2][row] * sc2;
                short4v pa4 = *(const short4v*)&pacc[w2][row][c4];
                o0 += bf2f((unsigned short)pa4[0]) * sc2;
                o1 += bf2f((unsigned short)pa4[1]) * sc2;
                o2 += bf2f((unsigned short)pa4[2]) * sc2;
                o3 += bf2f((unsigned short)pa4[3]) * sc2;
            }
            float invl = 1.0f / lt;
            float4 res = make_float4(o0 * invl, o1 * invl, o2 * invl, o3 * invl);
            *(float4*)&out[(size_t)(b * SEQ + qbase + row) * DOUT + c4] = res;
        }
        __syncthreads();
    }
}

// ---------------------------------------------------------------------------
extern "C" void kernel_launch(void* const* d_in, const int* in_sizes, int n_in,
                              void* d_out, int out_size, void* d_ws, size_t ws_size,
                              hipStream_t stream) {
    const float* x  = (const float*)d_in[0];
    const float* wq = (const float*)d_in[1];
    const float* bq = (const float*)d_in[2];
    const float* wk = (const float*)d_in[3];
    const float* bk = (const float*)d_in[4];
    const float* wv = (const float*)d_in[5];
    const float* bv = (const float*)d_in[6];
    float* out = (float*)d_out;

    char* ws = (char*)d_ws;
    unsigned short* wF = (unsigned short*)ws;                       // 294912 B
    unsigned short* Qf = (unsigned short*)(ws + 294912);            // 2 MB
    unsigned short* Kf = (unsigned short*)(ws + 294912 + 2097152);  // 2 MB
    unsigned short* Vf = (unsigned short*)(ws + 294912 + 4194304);  // 2 MB

    wprep_kernel<<<36, 256, 0, stream>>>(wq, wk, wv, wF);
    proj_kernel<<<512, 256, 0, stream>>>(x, bq, bk, bv, wF, Qf, Kf, Vf);
    attn_kernel<<<512, 512, 0, stream>>>(Qf, Kf, Vf, out);
}

// Round 24
// 48.165 us; speedup vs baseline: 1.0963x; 1.0114x over previous
//
#include <hip/hip_runtime.h>
#include <hip/hip_bf16.h>

#define BATCH 4
#define SEQ   4096
#define DIN   768
#define DOUT  64

typedef __attribute__((ext_vector_type(4))) float f32x4;
typedef __attribute__((ext_vector_type(8))) short short8;
typedef __attribute__((ext_vector_type(4))) short short4v;
typedef __attribute__((ext_vector_type(2))) unsigned uint2v;

#define QSCALE 0.18033688011112043f  /* 0.125 * log2(e) */

static __device__ __forceinline__ unsigned short f2bf(float f) {
    union { float f; unsigned u; } un; un.f = f;
    unsigned r = un.u + 0x7FFF + ((un.u >> 16) & 1);
    return (unsigned short)(r >> 16);
}
static __device__ __forceinline__ float bf2f(unsigned short h) {
    union { unsigned u; float f; } un; un.u = ((unsigned)h) << 16;
    return un.f;
}
// HW RTNE packed bf16 convert: lo -> bits[15:0], hi -> bits[31:16].
// Same rounding as f2bf but 1 instruction instead of ~10 (T12 recipe).
static __device__ __forceinline__ unsigned cvtpk(float lo, float hi) {
    unsigned r;
    asm("v_cvt_pk_bf16_f32 %0, %1, %2" : "=v"(r) : "v"(lo), "v"(hi));
    return r;
}

// ---------------------------------------------------------------------------
// Kernel 0 (v2): weights -> B-fragment order.
// ---------------------------------------------------------------------------
__global__ void wprep_kernel(const float* __restrict__ wq,
                             const float* __restrict__ wk,
                             const float* __restrict__ wv,
                             unsigned short* __restrict__ wF) {
    __shared__ float lds[64][65];
    int o = blockIdx.x / 12, kt = blockIdx.x % 12;
    const float* w = (o == 0) ? wq : (o == 1) ? wk : wv;
    int tid = threadIdx.x;
    int k0 = kt * 64;
    #pragma unroll
    for (int i = 0; i < 16; ++i) {
        int flat = tid + i * 256;
        int kl = flat >> 6, n = flat & 63;
        lds[kl][n] = w[(k0 + kl) * 64 + n];
    }
    __syncthreads();
    int lane = tid & 63;
    int m = lane & 15, g = lane >> 4;
    #pragma unroll
    for (int i = 0; i < 2; ++i) {
        int f = i * 4 + (tid >> 6);
        int t = f >> 1, kcl = f & 1;
        int kc = kt * 2 + kcl;
        int nc = o * 4 + t;
        short8 v;
        #pragma unroll
        for (int j = 0; j < 8; ++j)
            v[j] = (short)f2bf(lds[kcl * 32 + g * 8 + j][t * 16 + m]);
        *(short8*)&wF[(size_t)(nc * 24 + kc) * 512 + lane * 8] = v;
    }
}

// ---------------------------------------------------------------------------
// Kernel 1 (v9, round-19 best): QKV projection, 32 rows/block, 512 blocks,
// in-place rotated wF/af prefetch.
// ---------------------------------------------------------------------------
__global__ void __launch_bounds__(256) proj_kernel(
        const float* __restrict__ x,
        const float* __restrict__ bq,
        const float* __restrict__ bk,
        const float* __restrict__ bv,
        const unsigned short* __restrict__ wF,
        unsigned short* __restrict__ Qf,
        unsigned short* __restrict__ Kf,
        unsigned short* __restrict__ Vf) {
    __shared__ __align__(16) unsigned short xs[32][776];   // 48.5 KB
    __shared__ unsigned short tr[4][16][24];               // 3 KB

    int tid = threadIdx.x;
    int w = tid >> 6;
    int lane = tid & 63;
    int m = lane & 15, g = lane >> 4;
    int r0 = blockIdx.x * 32;

    {
        const float* xbase = x + (size_t)r0 * DIN;
        #pragma unroll
        for (int i = 0; i < 24; ++i) {
            int flat4 = tid + i * 256;
            int row = flat4 / 192;
            int c4 = flat4 - row * 192;
            float4 v = *(const float4*)(xbase + (size_t)row * DIN + c4 * 4);
            short4v sv;
            sv[0] = (short)f2bf(v.x); sv[1] = (short)f2bf(v.y);
            sv[2] = (short)f2bf(v.z); sv[3] = (short)f2bf(v.w);
            *(short4v*)&xs[row][c4 * 4] = sv;
        }
    }
    __syncthreads();

    f32x4 acc[2][3];
    #pragma unroll
    for (int st = 0; st < 2; ++st)
        #pragma unroll
        for (int t = 0; t < 3; ++t) acc[st][t] = (f32x4){0.f, 0.f, 0.f, 0.f};

    const unsigned short* wb0 = wF + (size_t)((w * 3 + 0) * 24) * 512 + lane * 8;
    const unsigned short* wb1 = wF + (size_t)((w * 3 + 1) * 24) * 512 + lane * 8;
    const unsigned short* wb2 = wF + (size_t)((w * 3 + 2) * 24) * 512 + lane * 8;

    short8 bf0 = *(const short8*)(wb0);
    short8 bf1 = *(const short8*)(wb1);
    short8 bf2 = *(const short8*)(wb2);
    short8 af0 = *(const short8*)&xs[m][g * 8];
    short8 af1 = *(const short8*)&xs[16 + m][g * 8];

    for (int kc = 0; kc < 24; ++kc) {
        short8 nb0, nb1, nb2, na0, na1;
        bool have = (kc + 1) < 24;
        if (have) {
            int off = (kc + 1) * 512;
            nb0 = *(const short8*)(wb0 + off);
            nb1 = *(const short8*)(wb1 + off);
            nb2 = *(const short8*)(wb2 + off);
            na0 = *(const short8*)&xs[m][(kc + 1) * 32 + g * 8];
            na1 = *(const short8*)&xs[16 + m][(kc + 1) * 32 + g * 8];
        }
        acc[0][0] = __builtin_amdgcn_mfma_f32_16x16x32_bf16(af0, bf0, acc[0][0], 0, 0, 0);
        acc[1][0] = __builtin_amdgcn_mfma_f32_16x16x32_bf16(af1, bf0, acc[1][0], 0, 0, 0);
        acc[0][1] = __builtin_amdgcn_mfma_f32_16x16x32_bf16(af0, bf1, acc[0][1], 0, 0, 0);
        acc[1][1] = __builtin_amdgcn_mfma_f32_16x16x32_bf16(af1, bf1, acc[1][1], 0, 0, 0);
        acc[0][2] = __builtin_amdgcn_mfma_f32_16x16x32_bf16(af0, bf2, acc[0][2], 0, 0, 0);
        acc[1][2] = __builtin_amdgcn_mfma_f32_16x16x32_bf16(af1, bf2, acc[1][2], 0, 0, 0);
        if (have) {
            bf0 = nb0; bf1 = nb1; bf2 = nb2;
            af0 = na0; af1 = na1;
        }
    }

    int b2 = r0 >> 12;
    int s = (r0 & 4095) >> 5;
    #pragma unroll
    for (int st = 0; st < 2; ++st) {
        #pragma unroll
        for (int tt = 0; tt < 3; ++tt) {
            int nc = w * 3 + tt;
            int o = nc >> 2;
            int t = nc & 3;
            const float* bias_p = (o == 0) ? bq : (o == 1) ? bk : bv;
            float bias = bias_p[t * 16 + m];
            #pragma unroll
            for (int r = 0; r < 4; ++r) {
                float val = acc[st][tt][r] + bias;
                if (o == 0) val *= QSCALE;
                tr[w][g * 4 + r][m] = f2bf(val);
            }
            if (o < 2) {
                if (g < 2) {
                    short8 v8;
                    #pragma unroll
                    for (int j = 0; j < 8; ++j) v8[j] = (short)tr[w][m][g * 8 + j];
                    unsigned short* dst = (o == 0) ? Qf : Kf;
                    int c = t >> 1;
                    *(short8*)&dst[(size_t)((blockIdx.x * 2 + st) * 2 + c) * 512
                                   + (((t & 1) * 2 + g) * 16 + m) * 8] = v8;
                }
            } else {
                if (g < 2) {
                    short8 v8;
                    #pragma unroll
                    for (int j = 0; j < 8; ++j) v8[j] = (short)tr[w][g * 8 + j][m];
                    *(short8*)&Vf[((size_t)(b2 * 128 + s) * 4 + t) * 512
                                  + ((st * 2 + g) * 16 + m) * 8] = v8;
                }
            }
        }
    }
}

// ---------------------------------------------------------------------------
// Kernel 2 (v13): round-19 best + (a) HW v_cvt_pk_bf16_f32 for P packing
// (replaces ~40 VALU ops/tile of manual RTNE on the exp2->ds_write chain
// with 4 instructions; identical rounding) and (b) s_setprio(1) around the
// MFMA clusters (T5 -- waves in this kernel are phase-independent, the
// configuration where setprio measured +4-7% on attention).
// ---------------------------------------------------------------------------
__global__ void __launch_bounds__(512, 2) attn_kernel(
        const unsigned short* __restrict__ Qf,
        const unsigned short* __restrict__ Kf,
        const unsigned short* __restrict__ Vf,
        float* __restrict__ out) {
    __shared__ __align__(16) unsigned short PT[8][16][40];
    __shared__ __align__(16) unsigned short pacc[8][16][68];
    __shared__ float pm[8][16];
    __shared__ float pl[8][16];

    int j = blockIdx.x;
    int b = j & 3;
    int qt = j >> 2;
    int base0 = qt * 16;
    int base1 = (255 - qt) * 16;
    int ns0 = (qt + 2) >> 1;
    int ns1 = (257 - qt) >> 1;
    int tid = threadIdx.x;
    int w = tid >> 6;
    int lane = tid & 63;
    int m = lane & 15, g = lane >> 4;

    const unsigned short* Q0 = Qf + (size_t)(b * 256 + qt) * 1024 + lane * 8;
    const unsigned short* Q1 = Qf + (size_t)(b * 256 + 255 - qt) * 1024 + lane * 8;
    short8 qf00 = *(const short8*)(Q0);
    short8 qf01 = *(const short8*)(Q0 + 512);
    short8 qf10 = *(const short8*)(Q1);
    short8 qf11 = *(const short8*)(Q1 + 512);

    short8 onesA;
    #pragma unroll
    for (int jj = 0; jj < 8; ++jj) onesA[jj] = (short)0x3F80;

    f32x4 acc[2][5];
    #pragma unroll
    for (int rt = 0; rt < 2; ++rt)
        #pragma unroll
        for (int t = 0; t < 5; ++t) acc[rt][t] = (f32x4){0.f, 0.f, 0.f, 0.f};
    float mrun0 = -INFINITY, mrun1 = -INFINITY;

    const unsigned short* Kbase = Kf + (size_t)(b * 256) * 1024 + lane * 8;
    const unsigned short* Vbase = Vf + (size_t)(b * 128) * 2048 + lane * 8;

    short8 kf[4], vf[4];
    if (w < ns1) {
        #pragma unroll
        for (int t = 0; t < 4; ++t) {
            kf[t] = *(const short8*)(Kbase + (size_t)w * 2048 + t * 512);
            vf[t] = *(const short8*)(Vbase + (size_t)w * 2048 + t * 512);
        }
    }

    for (int s = w; s < ns1; s += 8) {
        int kv0 = s * 32;
        int sn = s + 8;
        bool have = (sn < ns1);
        bool do0 = (s < ns0);

        if (do0) {
            f32x4 st0 = (f32x4){0.f, 0.f, 0.f, 0.f};
            f32x4 st1 = (f32x4){0.f, 0.f, 0.f, 0.f};
            __builtin_amdgcn_s_setprio(1);
            st0 = __builtin_amdgcn_mfma_f32_16x16x32_bf16(kf[0], qf00, st0, 0, 0, 0);
            st0 = __builtin_amdgcn_mfma_f32_16x16x32_bf16(kf[1], qf01, st0, 0, 0, 0);
            st1 = __builtin_amdgcn_mfma_f32_16x16x32_bf16(kf[2], qf00, st1, 0, 0, 0);
            st1 = __builtin_amdgcn_mfma_f32_16x16x32_bf16(kf[3], qf01, st1, 0, 0, 0);
            __builtin_amdgcn_s_setprio(0);
            if (s == ns0 - 1) {
                int q = base0 + m;
                #pragma unroll
                for (int r = 0; r < 4; ++r) {
                    if (kv0 + g * 4 + r > q)      st0[r] = -INFINITY;
                    if (kv0 + 16 + g * 4 + r > q) st1[r] = -INFINITY;
                }
            }
            float th = mrun0 + 8.0f;
            bool need = (st0[0] > th) | (st0[1] > th) | (st0[2] > th) | (st0[3] > th)
                      | (st1[0] > th) | (st1[1] > th) | (st1[2] > th) | (st1[3] > th);
            if (__any(need)) {
                float rmax = fmaxf(fmaxf(fmaxf(st0[0], st0[1]), fmaxf(st0[2], st0[3])),
                                   fmaxf(fmaxf(st1[0], st1[1]), fmaxf(st1[2], st1[3])));
                rmax = fmaxf(rmax, __shfl_xor(rmax, 16));
                rmax = fmaxf(rmax, __shfl_xor(rmax, 32));
                float mnew = fmaxf(mrun0, rmax);
                float alpha = __builtin_amdgcn_exp2f(mrun0 - mnew);
                mrun0 = mnew;
                #pragma unroll
                for (int t = 0; t < 5; ++t)
                    #pragma unroll
                    for (int r = 0; r < 4; ++r) acc[0][t][r] *= alpha;
            }
            float p00 = __builtin_amdgcn_exp2f(st0[0] - mrun0);
            float p01 = __builtin_amdgcn_exp2f(st0[1] - mrun0);
            float p02 = __builtin_amdgcn_exp2f(st0[2] - mrun0);
            float p03 = __builtin_amdgcn_exp2f(st0[3] - mrun0);
            float p10 = __builtin_amdgcn_exp2f(st1[0] - mrun0);
            float p11 = __builtin_amdgcn_exp2f(st1[1] - mrun0);
            float p12 = __builtin_amdgcn_exp2f(st1[2] - mrun0);
            float p13 = __builtin_amdgcn_exp2f(st1[3] - mrun0);
            *(uint2v*)&PT[w][m][g * 4]      = (uint2v){cvtpk(p00, p01), cvtpk(p02, p03)};
            *(uint2v*)&PT[w][m][16 + g * 4] = (uint2v){cvtpk(p10, p11), cvtpk(p12, p13)};
            short8 pb = *(const short8*)&PT[w][m][g * 8];
            __builtin_amdgcn_s_setprio(1);
            #pragma unroll
            for (int t = 0; t < 4; ++t)
                acc[0][t] = __builtin_amdgcn_mfma_f32_16x16x32_bf16(vf[t], pb, acc[0][t], 0, 0, 0);
            acc[0][4] = __builtin_amdgcn_mfma_f32_16x16x32_bf16(onesA, pb, acc[0][4], 0, 0, 0);
            __builtin_amdgcn_s_setprio(0);
        }

        {
            f32x4 st0 = (f32x4){0.f, 0.f, 0.f, 0.f};
            f32x4 st1 = (f32x4){0.f, 0.f, 0.f, 0.f};
            __builtin_amdgcn_s_setprio(1);
            st0 = __builtin_amdgcn_mfma_f32_16x16x32_bf16(kf[0], qf10, st0, 0, 0, 0);
            st0 = __builtin_amdgcn_mfma_f32_16x16x32_bf16(kf[1], qf11, st0, 0, 0, 0);
            st1 = __builtin_amdgcn_mfma_f32_16x16x32_bf16(kf[2], qf10, st1, 0, 0, 0);
            st1 = __builtin_amdgcn_mfma_f32_16x16x32_bf16(kf[3], qf11, st1, 0, 0, 0);
            __builtin_amdgcn_s_setprio(0);

            if (have) {
                #pragma unroll
                for (int t = 0; t < 4; ++t)
                    kf[t] = *(const short8*)(Kbase + (size_t)sn * 2048 + t * 512);
            }

            if (s == ns1 - 1) {
                int q = base1 + m;
                #pragma unroll
                for (int r = 0; r < 4; ++r) {
                    if (kv0 + g * 4 + r > q)      st0[r] = -INFINITY;
                    if (kv0 + 16 + g * 4 + r > q) st1[r] = -INFINITY;
                }
            }
            float th = mrun1 + 8.0f;
            bool need = (st0[0] > th) | (st0[1] > th) | (st0[2] > th) | (st0[3] > th)
                      | (st1[0] > th) | (st1[1] > th) | (st1[2] > th) | (st1[3] > th);
            if (__any(need)) {
                float rmax = fmaxf(fmaxf(fmaxf(st0[0], st0[1]), fmaxf(st0[2], st0[3])),
                                   fmaxf(fmaxf(st1[0], st1[1]), fmaxf(st1[2], st1[3])));
                rmax = fmaxf(rmax, __shfl_xor(rmax, 16));
                rmax = fmaxf(rmax, __shfl_xor(rmax, 32));
                float mnew = fmaxf(mrun1, rmax);
                float alpha = __builtin_amdgcn_exp2f(mrun1 - mnew);
                mrun1 = mnew;
                #pragma unroll
                for (int t = 0; t < 5; ++t)
                    #pragma unroll
                    for (int r = 0; r < 4; ++r) acc[1][t][r] *= alpha;
            }
            float p00 = __builtin_amdgcn_exp2f(st0[0] - mrun1);
            float p01 = __builtin_amdgcn_exp2f(st0[1] - mrun1);
            float p02 = __builtin_amdgcn_exp2f(st0[2] - mrun1);
            float p03 = __builtin_amdgcn_exp2f(st0[3] - mrun1);
            float p10 = __builtin_amdgcn_exp2f(st1[0] - mrun1);
            float p11 = __builtin_amdgcn_exp2f(st1[1] - mrun1);
            float p12 = __builtin_amdgcn_exp2f(st1[2] - mrun1);
            float p13 = __builtin_amdgcn_exp2f(st1[3] - mrun1);
            *(uint2v*)&PT[w][m][g * 4]      = (uint2v){cvtpk(p00, p01), cvtpk(p02, p03)};
            *(uint2v*)&PT[w][m][16 + g * 4] = (uint2v){cvtpk(p10, p11), cvtpk(p12, p13)};
            short8 pb = *(const short8*)&PT[w][m][g * 8];
            __builtin_amdgcn_s_setprio(1);
            #pragma unroll
            for (int t = 0; t < 4; ++t)
                acc[1][t] = __builtin_amdgcn_mfma_f32_16x16x32_bf16(vf[t], pb, acc[1][t], 0, 0, 0);
            acc[1][4] = __builtin_amdgcn_mfma_f32_16x16x32_bf16(onesA, pb, acc[1][4], 0, 0, 0);
            __builtin_amdgcn_s_setprio(0);

            if (have) {
                #pragma unroll
                for (int t = 0; t < 4; ++t)
                    vf[t] = *(const short8*)(Vbase + (size_t)sn * 2048 + t * 512);
            }
        }
    }

    #pragma unroll
    for (int rt = 0; rt < 2; ++rt) {
        int qbase = (rt == 0) ? base0 : base1;
        float mr = (rt == 0) ? mrun0 : mrun1;
        if (lane < 16) {
            pm[w][m] = mr;
            pl[w][m] = acc[rt][4][0];
        }
        #pragma unroll
        for (int t = 0; t < 4; ++t)
            #pragma unroll
            for (int r = 0; r < 4; ++r)
                pacc[w][m][t * 16 + g * 4 + r] = f2bf(acc[rt][t][r]);
        __syncthreads();

        if (tid < 256) {
            int row = tid >> 4;
            int c4 = (tid & 15) * 4;
            float mmax = pm[0][row];
            #pragma unroll
            for (int w2 = 1; w2 < 8; ++w2) mmax = fmaxf(mmax, pm[w2][row]);
            float lt = 0.f;
            float o0 = 0.f, o1 = 0.f, o2 = 0.f, o3 = 0.f;
            #pragma unroll
            for (int w2 = 0; w2 < 8; ++w2) {
                float sc2 = __builtin_amdgcn_exp2f(pm[w2][row] - mmax);
                lt += pl[w2][row] * sc2;
                short4v pa4 = *(const short4v*)&pacc[w2][row][c4];
                o0 += bf2f((unsigned short)pa4[0]) * sc2;
                o1 += bf2f((unsigned short)pa4[1]) * sc2;
                o2 += bf2f((unsigned short)pa4[2]) * sc2;
                o3 += bf2f((unsigned short)pa4[3]) * sc2;
            }
            float invl = 1.0f / lt;
            float4 res = make_float4(o0 * invl, o1 * invl, o2 * invl, o3 * invl);
            *(float4*)&out[(size_t)(b * SEQ + qbase + row) * DOUT + c4] = res;
        }
        __syncthreads();
    }
}

// ---------------------------------------------------------------------------
extern "C" void kernel_launch(void* const* d_in, const int* in_sizes, int n_in,
                              void* d_out, int out_size, void* d_ws, size_t ws_size,
                              hipStream_t stream) {
    const float* x  = (const float*)d_in[0];
    const float* wq = (const float*)d_in[1];
    const float* bq = (const float*)d_in[2];
    const float* wk = (const float*)d_in[3];
    const float* bk = (const float*)d_in[4];
    const float* wv = (const float*)d_in[5];
    const float* bv = (const float*)d_in[6];
    float* out = (float*)d_out;

    char* ws = (char*)d_ws;
    unsigned short* wF = (unsigned short*)ws;                       // 294912 B
    unsigned short* Qf = (unsigned short*)(ws + 294912);            // 2 MB
    unsigned short* Kf = (unsigned short*)(ws + 294912 + 2097152);  // 2 MB
    unsigned short* Vf = (unsigned short*)(ws + 294912 + 4194304);  // 2 MB

    wprep_kernel<<<36, 256, 0, stream>>>(wq, wk, wv, wF);
    proj_kernel<<<512, 256, 0, stream>>>(x, bq, bk, bv, wF, Qf, Kf, Vf);
    attn_kernel<<<512, 512, 0, stream>>>(Qf, Kf, Vf, out);
}

// Round 25
// 48.076 us; speedup vs baseline: 1.0983x; 1.0019x over previous
//
#include <hip/hip_runtime.h>
#include <hip/hip_bf16.h>

#define BATCH 4
#define SEQ   4096
#define DIN   768
#define DOUT  64

typedef __attribute__((ext_vector_type(4))) float f32x4;
typedef __attribute__((ext_vector_type(8))) short short8;
typedef __attribute__((ext_vector_type(4))) short short4v;
typedef __attribute__((ext_vector_type(2))) unsigned uint2v;

#define QSCALE 0.18033688011112043f  /* 0.125 * log2(e) */

static __device__ __forceinline__ unsigned short f2bf(float f) {
    union { float f; unsigned u; } un; un.f = f;
    unsigned r = un.u + 0x7FFF + ((un.u >> 16) & 1);
    return (unsigned short)(r >> 16);
}
static __device__ __forceinline__ float bf2f(unsigned short h) {
    union { unsigned u; float f; } un; un.u = ((unsigned)h) << 16;
    return un.f;
}
// HW RTNE packed bf16 convert: lo -> bits[15:0], hi -> bits[31:16].
static __device__ __forceinline__ unsigned cvtpk(float lo, float hi) {
    unsigned r;
    asm("v_cvt_pk_bf16_f32 %0, %1, %2" : "=v"(r) : "v"(lo), "v"(hi));
    return r;
}

// ---------------------------------------------------------------------------
// Kernel 0 (v3): weights -> B-fragment order; cvtpk packing.
// ---------------------------------------------------------------------------
__global__ void wprep_kernel(const float* __restrict__ wq,
                             const float* __restrict__ wk,
                             const float* __restrict__ wv,
                             unsigned short* __restrict__ wF) {
    __shared__ float lds[64][65];
    int o = blockIdx.x / 12, kt = blockIdx.x % 12;
    const float* w = (o == 0) ? wq : (o == 1) ? wk : wv;
    int tid = threadIdx.x;
    int k0 = kt * 64;
    #pragma unroll
    for (int i = 0; i < 16; ++i) {
        int flat = tid + i * 256;
        int kl = flat >> 6, n = flat & 63;
        lds[kl][n] = w[(k0 + kl) * 64 + n];
    }
    __syncthreads();
    int lane = tid & 63;
    int m = lane & 15, g = lane >> 4;
    #pragma unroll
    for (int i = 0; i < 2; ++i) {
        int f = i * 4 + (tid >> 6);
        int t = f >> 1, kcl = f & 1;
        int kc = kt * 2 + kcl;
        int nc = o * 4 + t;
        unsigned pk[4];
        #pragma unroll
        for (int j = 0; j < 4; ++j)
            pk[j] = cvtpk(lds[kcl * 32 + g * 8 + 2 * j][t * 16 + m],
                          lds[kcl * 32 + g * 8 + 2 * j + 1][t * 16 + m]);
        uint2v* dst = (uint2v*)&wF[(size_t)(nc * 24 + kc) * 512 + lane * 8];
        dst[0] = (uint2v){pk[0], pk[1]};
        dst[1] = (uint2v){pk[2], pk[3]};
    }
}

// ---------------------------------------------------------------------------
// Kernel 1 (v10): QKV projection, 32 rows/block, 512 blocks, in-place
// rotated wF/af prefetch. NEW: x-staging conversion via cvtpk (2 HW ops +
// 1 b64 store per float4, was ~4 f2bf chains + scalar stores) — staging is
// pre-barrier serial work on proj's critical path.
// ---------------------------------------------------------------------------
__global__ void __launch_bounds__(256) proj_kernel(
        const float* __restrict__ x,
        const float* __restrict__ bq,
        const float* __restrict__ bk,
        const float* __restrict__ bv,
        const unsigned short* __restrict__ wF,
        unsigned short* __restrict__ Qf,
        unsigned short* __restrict__ Kf,
        unsigned short* __restrict__ Vf) {
    __shared__ __align__(16) unsigned short xs[32][776];   // 48.5 KB
    __shared__ unsigned short tr[4][16][24];               // 3 KB

    int tid = threadIdx.x;
    int w = tid >> 6;
    int lane = tid & 63;
    int m = lane & 15, g = lane >> 4;
    int r0 = blockIdx.x * 32;

    {
        const float* xbase = x + (size_t)r0 * DIN;
        #pragma unroll
        for (int i = 0; i < 24; ++i) {
            int flat4 = tid + i * 256;
            int row = flat4 / 192;
            int c4 = flat4 - row * 192;
            float4 v = *(const float4*)(xbase + (size_t)row * DIN + c4 * 4);
            *(uint2v*)&xs[row][c4 * 4] = (uint2v){cvtpk(v.x, v.y), cvtpk(v.z, v.w)};
        }
    }
    __syncthreads();

    f32x4 acc[2][3];
    #pragma unroll
    for (int st = 0; st < 2; ++st)
        #pragma unroll
        for (int t = 0; t < 3; ++t) acc[st][t] = (f32x4){0.f, 0.f, 0.f, 0.f};

    const unsigned short* wb0 = wF + (size_t)((w * 3 + 0) * 24) * 512 + lane * 8;
    const unsigned short* wb1 = wF + (size_t)((w * 3 + 1) * 24) * 512 + lane * 8;
    const unsigned short* wb2 = wF + (size_t)((w * 3 + 2) * 24) * 512 + lane * 8;

    short8 bf0 = *(const short8*)(wb0);
    short8 bf1 = *(const short8*)(wb1);
    short8 bf2 = *(const short8*)(wb2);
    short8 af0 = *(const short8*)&xs[m][g * 8];
    short8 af1 = *(const short8*)&xs[16 + m][g * 8];

    for (int kc = 0; kc < 24; ++kc) {
        short8 nb0, nb1, nb2, na0, na1;
        bool have = (kc + 1) < 24;
        if (have) {
            int off = (kc + 1) * 512;
            nb0 = *(const short8*)(wb0 + off);
            nb1 = *(const short8*)(wb1 + off);
            nb2 = *(const short8*)(wb2 + off);
            na0 = *(const short8*)&xs[m][(kc + 1) * 32 + g * 8];
            na1 = *(const short8*)&xs[16 + m][(kc + 1) * 32 + g * 8];
        }
        acc[0][0] = __builtin_amdgcn_mfma_f32_16x16x32_bf16(af0, bf0, acc[0][0], 0, 0, 0);
        acc[1][0] = __builtin_amdgcn_mfma_f32_16x16x32_bf16(af1, bf0, acc[1][0], 0, 0, 0);
        acc[0][1] = __builtin_amdgcn_mfma_f32_16x16x32_bf16(af0, bf1, acc[0][1], 0, 0, 0);
        acc[1][1] = __builtin_amdgcn_mfma_f32_16x16x32_bf16(af1, bf1, acc[1][1], 0, 0, 0);
        acc[0][2] = __builtin_amdgcn_mfma_f32_16x16x32_bf16(af0, bf2, acc[0][2], 0, 0, 0);
        acc[1][2] = __builtin_amdgcn_mfma_f32_16x16x32_bf16(af1, bf2, acc[1][2], 0, 0, 0);
        if (have) {
            bf0 = nb0; bf1 = nb1; bf2 = nb2;
            af0 = na0; af1 = na1;
        }
    }

    int b2 = r0 >> 12;
    int s = (r0 & 4095) >> 5;
    #pragma unroll
    for (int st = 0; st < 2; ++st) {
        #pragma unroll
        for (int tt = 0; tt < 3; ++tt) {
            int nc = w * 3 + tt;
            int o = nc >> 2;
            int t = nc & 3;
            const float* bias_p = (o == 0) ? bq : (o == 1) ? bk : bv;
            float bias = bias_p[t * 16 + m];
            #pragma unroll
            for (int r = 0; r < 4; ++r) {
                float val = acc[st][tt][r] + bias;
                if (o == 0) val *= QSCALE;
                tr[w][g * 4 + r][m] = f2bf(val);
            }
            if (o < 2) {
                if (g < 2) {
                    short8 v8;
                    #pragma unroll
                    for (int j = 0; j < 8; ++j) v8[j] = (short)tr[w][m][g * 8 + j];
                    unsigned short* dst = (o == 0) ? Qf : Kf;
                    int c = t >> 1;
                    *(short8*)&dst[(size_t)((blockIdx.x * 2 + st) * 2 + c) * 512
                                   + (((t & 1) * 2 + g) * 16 + m) * 8] = v8;
                }
            } else {
                if (g < 2) {
                    short8 v8;
                    #pragma unroll
                    for (int j = 0; j < 8; ++j) v8[j] = (short)tr[w][g * 8 + j][m];
                    *(short8*)&Vf[((size_t)(b2 * 128 + s) * 4 + t) * 512
                                  + ((st * 2 + g) * 16 + m) * 8] = v8;
                }
            }
        }
    }
}

// ---------------------------------------------------------------------------
// Kernel 2 (v14): round-24 state + cvtpk-packed pacc epilogue writes.
// ---------------------------------------------------------------------------
__global__ void __launch_bounds__(512, 2) attn_kernel(
        const unsigned short* __restrict__ Qf,
        const unsigned short* __restrict__ Kf,
        const unsigned short* __restrict__ Vf,
        float* __restrict__ out) {
    __shared__ __align__(16) unsigned short PT[8][16][40];
    __shared__ __align__(16) unsigned short pacc[8][16][68];
    __shared__ float pm[8][16];
    __shared__ float pl[8][16];

    int j = blockIdx.x;
    int b = j & 3;
    int qt = j >> 2;
    int base0 = qt * 16;
    int base1 = (255 - qt) * 16;
    int ns0 = (qt + 2) >> 1;
    int ns1 = (257 - qt) >> 1;
    int tid = threadIdx.x;
    int w = tid >> 6;
    int lane = tid & 63;
    int m = lane & 15, g = lane >> 4;

    const unsigned short* Q0 = Qf + (size_t)(b * 256 + qt) * 1024 + lane * 8;
    const unsigned short* Q1 = Qf + (size_t)(b * 256 + 255 - qt) * 1024 + lane * 8;
    short8 qf00 = *(const short8*)(Q0);
    short8 qf01 = *(const short8*)(Q0 + 512);
    short8 qf10 = *(const short8*)(Q1);
    short8 qf11 = *(const short8*)(Q1 + 512);

    short8 onesA;
    #pragma unroll
    for (int jj = 0; jj < 8; ++jj) onesA[jj] = (short)0x3F80;

    f32x4 acc[2][5];
    #pragma unroll
    for (int rt = 0; rt < 2; ++rt)
        #pragma unroll
        for (int t = 0; t < 5; ++t) acc[rt][t] = (f32x4){0.f, 0.f, 0.f, 0.f};
    float mrun0 = -INFINITY, mrun1 = -INFINITY;

    const unsigned short* Kbase = Kf + (size_t)(b * 256) * 1024 + lane * 8;
    const unsigned short* Vbase = Vf + (size_t)(b * 128) * 2048 + lane * 8;

    short8 kf[4], vf[4];
    if (w < ns1) {
        #pragma unroll
        for (int t = 0; t < 4; ++t) {
            kf[t] = *(const short8*)(Kbase + (size_t)w * 2048 + t * 512);
            vf[t] = *(const short8*)(Vbase + (size_t)w * 2048 + t * 512);
        }
    }

    for (int s = w; s < ns1; s += 8) {
        int kv0 = s * 32;
        int sn = s + 8;
        bool have = (sn < ns1);
        bool do0 = (s < ns0);

        if (do0) {
            f32x4 st0 = (f32x4){0.f, 0.f, 0.f, 0.f};
            f32x4 st1 = (f32x4){0.f, 0.f, 0.f, 0.f};
            __builtin_amdgcn_s_setprio(1);
            st0 = __builtin_amdgcn_mfma_f32_16x16x32_bf16(kf[0], qf00, st0, 0, 0, 0);
            st0 = __builtin_amdgcn_mfma_f32_16x16x32_bf16(kf[1], qf01, st0, 0, 0, 0);
            st1 = __builtin_amdgcn_mfma_f32_16x16x32_bf16(kf[2], qf00, st1, 0, 0, 0);
            st1 = __builtin_amdgcn_mfma_f32_16x16x32_bf16(kf[3], qf01, st1, 0, 0, 0);
            __builtin_amdgcn_s_setprio(0);
            if (s == ns0 - 1) {
                int q = base0 + m;
                #pragma unroll
                for (int r = 0; r < 4; ++r) {
                    if (kv0 + g * 4 + r > q)      st0[r] = -INFINITY;
                    if (kv0 + 16 + g * 4 + r > q) st1[r] = -INFINITY;
                }
            }
            float th = mrun0 + 8.0f;
            bool need = (st0[0] > th) | (st0[1] > th) | (st0[2] > th) | (st0[3] > th)
                      | (st1[0] > th) | (st1[1] > th) | (st1[2] > th) | (st1[3] > th);
            if (__any(need)) {
                float rmax = fmaxf(fmaxf(fmaxf(st0[0], st0[1]), fmaxf(st0[2], st0[3])),
                                   fmaxf(fmaxf(st1[0], st1[1]), fmaxf(st1[2], st1[3])));
                rmax = fmaxf(rmax, __shfl_xor(rmax, 16));
                rmax = fmaxf(rmax, __shfl_xor(rmax, 32));
                float mnew = fmaxf(mrun0, rmax);
                float alpha = __builtin_amdgcn_exp2f(mrun0 - mnew);
                mrun0 = mnew;
                #pragma unroll
                for (int t = 0; t < 5; ++t)
                    #pragma unroll
                    for (int r = 0; r < 4; ++r) acc[0][t][r] *= alpha;
            }
            float p00 = __builtin_amdgcn_exp2f(st0[0] - mrun0);
            float p01 = __builtin_amdgcn_exp2f(st0[1] - mrun0);
            float p02 = __builtin_amdgcn_exp2f(st0[2] - mrun0);
            float p03 = __builtin_amdgcn_exp2f(st0[3] - mrun0);
            float p10 = __builtin_amdgcn_exp2f(st1[0] - mrun0);
            float p11 = __builtin_amdgcn_exp2f(st1[1] - mrun0);
            float p12 = __builtin_amdgcn_exp2f(st1[2] - mrun0);
            float p13 = __builtin_amdgcn_exp2f(st1[3] - mrun0);
            *(uint2v*)&PT[w][m][g * 4]      = (uint2v){cvtpk(p00, p01), cvtpk(p02, p03)};
            *(uint2v*)&PT[w][m][16 + g * 4] = (uint2v){cvtpk(p10, p11), cvtpk(p12, p13)};
            short8 pb = *(const short8*)&PT[w][m][g * 8];
            __builtin_amdgcn_s_setprio(1);
            #pragma unroll
            for (int t = 0; t < 4; ++t)
                acc[0][t] = __builtin_amdgcn_mfma_f32_16x16x32_bf16(vf[t], pb, acc[0][t], 0, 0, 0);
            acc[0][4] = __builtin_amdgcn_mfma_f32_16x16x32_bf16(onesA, pb, acc[0][4], 0, 0, 0);
            __builtin_amdgcn_s_setprio(0);
        }

        {
            f32x4 st0 = (f32x4){0.f, 0.f, 0.f, 0.f};
            f32x4 st1 = (f32x4){0.f, 0.f, 0.f, 0.f};
            __builtin_amdgcn_s_setprio(1);
            st0 = __builtin_amdgcn_mfma_f32_16x16x32_bf16(kf[0], qf10, st0, 0, 0, 0);
            st0 = __builtin_amdgcn_mfma_f32_16x16x32_bf16(kf[1], qf11, st0, 0, 0, 0);
            st1 = __builtin_amdgcn_mfma_f32_16x16x32_bf16(kf[2], qf10, st1, 0, 0, 0);
            st1 = __builtin_amdgcn_mfma_f32_16x16x32_bf16(kf[3], qf11, st1, 0, 0, 0);
            __builtin_amdgcn_s_setprio(0);

            if (have) {
                #pragma unroll
                for (int t = 0; t < 4; ++t)
                    kf[t] = *(const short8*)(Kbase + (size_t)sn * 2048 + t * 512);
            }

            if (s == ns1 - 1) {
                int q = base1 + m;
                #pragma unroll
                for (int r = 0; r < 4; ++r) {
                    if (kv0 + g * 4 + r > q)      st0[r] = -INFINITY;
                    if (kv0 + 16 + g * 4 + r > q) st1[r] = -INFINITY;
                }
            }
            float th = mrun1 + 8.0f;
            bool need = (st0[0] > th) | (st0[1] > th) | (st0[2] > th) | (st0[3] > th)
                      | (st1[0] > th) | (st1[1] > th) | (st1[2] > th) | (st1[3] > th);
            if (__any(need)) {
                float rmax = fmaxf(fmaxf(fmaxf(st0[0], st0[1]), fmaxf(st0[2], st0[3])),
                                   fmaxf(fmaxf(st1[0], st1[1]), fmaxf(st1[2], st1[3])));
                rmax = fmaxf(rmax, __shfl_xor(rmax, 16));
                rmax = fmaxf(rmax, __shfl_xor(rmax, 32));
                float mnew = fmaxf(mrun1, rmax);
                float alpha = __builtin_amdgcn_exp2f(mrun1 - mnew);
                mrun1 = mnew;
                #pragma unroll
                for (int t = 0; t < 5; ++t)
                    #pragma unroll
                    for (int r = 0; r < 4; ++r) acc[1][t][r] *= alpha;
            }
            float p00 = __builtin_amdgcn_exp2f(st0[0] - mrun1);
            float p01 = __builtin_amdgcn_exp2f(st0[1] - mrun1);
            float p02 = __builtin_amdgcn_exp2f(st0[2] - mrun1);
            float p03 = __builtin_amdgcn_exp2f(st0[3] - mrun1);
            float p10 = __builtin_amdgcn_exp2f(st1[0] - mrun1);
            float p11 = __builtin_amdgcn_exp2f(st1[1] - mrun1);
            float p12 = __builtin_amdgcn_exp2f(st1[2] - mrun1);
            float p13 = __builtin_amdgcn_exp2f(st1[3] - mrun1);
            *(uint2v*)&PT[w][m][g * 4]      = (uint2v){cvtpk(p00, p01), cvtpk(p02, p03)};
            *(uint2v*)&PT[w][m][16 + g * 4] = (uint2v){cvtpk(p10, p11), cvtpk(p12, p13)};
            short8 pb = *(const short8*)&PT[w][m][g * 8];
            __builtin_amdgcn_s_setprio(1);
            #pragma unroll
            for (int t = 0; t < 4; ++t)
                acc[1][t] = __builtin_amdgcn_mfma_f32_16x16x32_bf16(vf[t], pb, acc[1][t], 0, 0, 0);
            acc[1][4] = __builtin_amdgcn_mfma_f32_16x16x32_bf16(onesA, pb, acc[1][4], 0, 0, 0);
            __builtin_amdgcn_s_setprio(0);

            if (have) {
                #pragma unroll
                for (int t = 0; t < 4; ++t)
                    vf[t] = *(const short8*)(Vbase + (size_t)sn * 2048 + t * 512);
            }
        }
    }

    #pragma unroll
    for (int rt = 0; rt < 2; ++rt) {
        int qbase = (rt == 0) ? base0 : base1;
        float mr = (rt == 0) ? mrun0 : mrun1;
        if (lane < 16) {
            pm[w][m] = mr;
            pl[w][m] = acc[rt][4][0];
        }
        #pragma unroll
        for (int t = 0; t < 4; ++t)
            *(uint2v*)&pacc[w][m][t * 16 + g * 4] =
                (uint2v){cvtpk(acc[rt][t][0], acc[rt][t][1]),
                         cvtpk(acc[rt][t][2], acc[rt][t][3])};
        __syncthreads();

        if (tid < 256) {
            int row = tid >> 4;
            int c4 = (tid & 15) * 4;
            float mmax = pm[0][row];
            #pragma unroll
            for (int w2 = 1; w2 < 8; ++w2) mmax = fmaxf(mmax, pm[w2][row]);
            float lt = 0.f;
            float o0 = 0.f, o1 = 0.f, o2 = 0.f, o3 = 0.f;
            #pragma unroll
            for (int w2 = 0; w2 < 8; ++w2) {
                float sc2 = __builtin_amdgcn_exp2f(pm[w2][row] - mmax);
                lt += pl[w2][row] * sc2;
                short4v pa4 = *(const short4v*)&pacc[w2][row][c4];
                o0 += bf2f((unsigned short)pa4[0]) * sc2;
                o1 += bf2f((unsigned short)pa4[1]) * sc2;
                o2 += bf2f((unsigned short)pa4[2]) * sc2;
                o3 += bf2f((unsigned short)pa4[3]) * sc2;
            }
            float invl = 1.0f / lt;
            float4 res = make_float4(o0 * invl, o1 * invl, o2 * invl, o3 * invl);
            *(float4*)&out[(size_t)(b * SEQ + qbase + row) * DOUT + c4] = res;
        }
        __syncthreads();
    }
}

// ---------------------------------------------------------------------------
extern "C" void kernel_launch(void* const* d_in, const int* in_sizes, int n_in,
                              void* d_out, int out_size, void* d_ws, size_t ws_size,
                              hipStream_t stream) {
    const float* x  = (const float*)d_in[0];
    const float* wq = (const float*)d_in[1];
    const float* bq = (const float*)d_in[2];
    const float* wk = (const float*)d_in[3];
    const float* bk = (const float*)d_in[4];
    const float* wv = (const float*)d_in[5];
    const float* bv = (const float*)d_in[6];
    float* out = (float*)d_out;

    char* ws = (char*)d_ws;
    unsigned short* wF = (unsigned short*)ws;                       // 294912 B
    unsigned short* Qf = (unsigned short*)(ws + 294912);            // 2 MB
    unsigned short* Kf = (unsigned short*)(ws + 294912 + 2097152);  // 2 MB
    unsigned short* Vf = (unsigned short*)(ws + 294912 + 4194304);  // 2 MB

    wprep_kernel<<<36, 256, 0, stream>>>(wq, wk, wv, wF);
    proj_kernel<<<512, 256, 0, stream>>>(x, bq, bk, bv, wF, Qf, Kf, Vf);
    attn_kernel<<<512, 512, 0, stream>>>(Qf, Kf, Vf, out);
}